// Round 11
// baseline (302.026 us; speedup 1.0000x reference)
//
#include <hip/hip_runtime.h>
#include <hip/hip_bf16.h>

// MixingBlock round 11: R9 base (TB=64, 512thr, 1 block/CU). Vec GEMMs
// re-tiled 3d x 4col per wave (LDS A-reads /4, B from L2), prefetch rings
// dropped, staging bank conflicts fixed (unit-interleaved lane mapping).

typedef __attribute__((ext_vector_type(8))) short short8;
typedef __attribute__((ext_vector_type(4))) float f32x4;
typedef unsigned short u16;

#define B_   8
#define N_   2048
#define EPS_ 1e-6f
#define TB   64

// ws element offsets (bf16)
#define OFF_CS 0        // wt_cs [256][1152]  (k*384 col blocks: [s_win|vdot])
#define OFF_V  294912   // wt_v  [128][768]   (k*256: [vwin(128)|cross(128)])
#define OFF_G  393216   // wt_g  [128][768]   (k*256: s_rhat weights)
#define OFF_SS 491520   // wt_ss [256][256]
#define OFF_SV 557056   // wt_sv [128][128]

#define MFMA(a,b,c) __builtin_amdgcn_mfma_f32_16x16x32_bf16((a),(b),(c),0,0,0)

__device__ __forceinline__ u16 f2b(float v){ __hip_bfloat16 h=__float2bfloat16(v); return *(u16*)&h; }

// ---------------- weight prep: transpose + remap + f32->bf16 ----------------
__global__ __launch_bounds__(256) void prep_weights(
    const float* __restrict__ Wcs, const float* __restrict__ Wcv,
    const float* __restrict__ Wss, const float* __restrict__ Wsv,
    u16* __restrict__ ws)
{
    const int bid = blockIdx.x;
    const float* src; int N, r0, ld, c0; u16* dst; int tile;
    if (bid < 288)      { src=Wcs; N=256; r0=0; dst=ws+OFF_CS; ld=1152; c0=0; tile=bid; }
    else if (bid < 336) { int k=(bid-288)/16; tile=(bid-288)%16;
                          src=Wcv; N=128; r0=k*512;     dst=ws+OFF_V; ld=768; c0=k*256; }
    else if (bid < 432) { int k=(bid-336)/32; tile=(bid-336)%32;
                          src=Wcv; N=128; r0=k*512+128; dst=ws+OFF_G; ld=768; c0=k*256; }
    else if (bid < 480) { int k=(bid-432)/16; tile=(bid-432)%16;
                          src=Wcv; N=128; r0=k*512+384; dst=ws+OFF_V; ld=768; c0=k*256+128; }
    else if (bid < 544) { tile=bid-480; src=Wss; N=256; r0=0; dst=ws+OFF_SS; ld=256; c0=0; }
    else                { tile=bid-544; src=Wsv; N=128; r0=0; dst=ws+OFF_SV; ld=128; c0=0; }
    const int ntN = N >> 5;
    const int kt = (tile/ntN)*32, nn = (tile%ntN)*32;
    __shared__ float t[32][33];
    const int r = threadIdx.x >> 5, c = threadIdx.x & 31;
#pragma unroll
    for (int i = 0; i < 4; ++i)
        t[r+8*i][c] = src[(size_t)(r0+kt+r+8*i)*N + nn+c];
    __syncthreads();
#pragma unroll
    for (int i = 0; i < 4; ++i)
        dst[(size_t)(nn+r+8*i)*ld + c0+kt+c] = f2b(t[c][r+8*i]);
}

// LN reduce: 8 waves, 4 m-frags (64 tokens). Butterfly over 16 lanes + red.
__device__ __forceinline__ void ln_reduce(
    float p1[4][4], float p2[4][4], float pv[4][4], f32x4* red,
    int lm, int lq4, int w, float mu[4][4], float ss[4][4], float vs[4][4])
{
    __syncthreads();
#pragma unroll
    for (int m2 = 1; m2 < 16; m2 <<= 1)
#pragma unroll
        for (int m = 0; m < 4; ++m)
#pragma unroll
            for (int q = 0; q < 4; ++q) {
                p1[m][q] += __shfl_xor(p1[m][q], m2);
                p2[m][q] += __shfl_xor(p2[m][q], m2);
                pv[m][q] += __shfl_xor(pv[m][q], m2);
            }
    if (lm == 0)
#pragma unroll
        for (int m = 0; m < 4; ++m)
#pragma unroll
            for (int q = 0; q < 4; ++q) {
                f32x4 r = {p1[m][q], p2[m][q], pv[m][q], 0.f};
                red[(m*16+lq4+q)*8 + w] = r;
            }
    __syncthreads();
#pragma unroll
    for (int m = 0; m < 4; ++m)
#pragma unroll
        for (int q = 0; q < 4; ++q) {
            const int t = m*16 + lq4 + q;
            f32x4 rs = red[t*8+0];
#pragma unroll
            for (int i = 1; i < 8; ++i) rs += red[t*8+i];
            const float mm = rs.x * (1.f/256.f);
            mu[m][q] = mm;
            ss[m][q] = rsqrtf(rs.y*(1.f/256.f) - mm*mm + EPS_);
            vs[m][q] = rsqrtf(rs.z*(1.f/128.f) + EPS_);
        }
}

__global__ __launch_bounds__(512, 2) void mixing_main(
    const float* __restrict__ x_s, const float* __restrict__ x_v,
    const float* __restrict__ coords, const u16* __restrict__ wt,
    float* __restrict__ out)
{
    // fs [64][392]u16 @0 | fv [192][264]u16 @50176 | rhp @151552 | red @154624
    // aliases: hsb [64][264]@0, hvb [192][136]@50176, xvL [64*384]f32 @50176
    __shared__ __align__(16) char smem[162816];
    u16*   fs  = (u16*)smem;
    u16*   fv  = (u16*)(smem + 50176);
    u16*   hsb = (u16*)smem;
    u16*   hvb = (u16*)(smem + 50176);
    float* xvL = (float*)(smem + 50176);
    float* rhp = (float*)(smem + 151552);
    f32x4* red = (f32x4*)(smem + 154624);

    const int tid = threadIdx.x;
    const int w   = tid >> 6, l = tid & 63;
    const int lm  = l & 15, lk8 = (l >> 4) << 3, lq4 = (l >> 4) << 2;
    const int tq  = w >> 1;          // token quarter (vec ownership)
    const int ch  = w & 1;           // col half (vec ownership)
    const int gt0 = blockIdx.x * TB;
    const int n0  = gt0 & (N_ - 1);
    const int seq0 = gt0 - n0;
    const size_t ZV0 = (size_t)B_ * N_ * 256;

    // rhat [64 t][3 k]
    if (tid < 192) {
        const int t = tid / 3, k = tid - 3 * (tid / 3);
        const int jn = n0 + t + k - 1;
        const int jc = jn < 0 ? 0 : (jn > N_-1 ? N_-1 : jn);
        const float* cj = coords + (size_t)(seq0 + jc) * 3;
        const float* c0p = coords + (size_t)(gt0 + t) * 3;
        const float d0 = cj[0]-c0p[0], d1 = cj[1]-c0p[1], d2 = cj[2]-c0p[2];
        const float dn = sqrtf(d0*d0 + d1*d1 + d2*d2);
        const float inv = dn > 1e-6f ? 1.f/dn : 0.f;
        rhp[(t*3+k)*4+0] = d0*inv; rhp[(t*3+k)*4+1] = d1*inv; rhp[(t*3+k)*4+2] = d2*inv;
    }
    __syncthreads();

    const f32x4 fz = {0.f,0.f,0.f,0.f};
    f32x4 acc_s[4][2];                 // [m][u], cols (2w+u)*16+lm
    f32x4 accv[3][4];                  // [d][j]: tokens tq*16, cols ch*64+j*16+lm
#pragma unroll
    for (int m = 0; m < 4; ++m) { acc_s[m][0] = fz; acc_s[m][1] = fz; }
#pragma unroll
    for (int d = 0; d < 3; ++d)
#pragma unroll
        for (int j = 0; j < 4; ++j) accv[d][j] = fz;

    const int bt = tid >> 3;   // token 0..63 (8 thr/token)
    const int bx = tid & 7;

#pragma unroll 1
    for (int k = 0; k < 3; ++k) {
        const int jn = n0 + bt + k - 1;
        const bool valid = (unsigned)jn < (unsigned)N_;
        const size_t j = (size_t)seq0 + (valid ? jn : 0);
        // ---- s_win: 4 x 8ch stripes at 64-ch stride (units bx+8s: 2-way free)
#pragma unroll
        for (int s = 0; s < 4; ++s) {
            const int cc = bx*8 + s*64;
            float v[8];
            if (valid) {
                const float4* sp = (const float4*)(x_s + j*256 + cc);
                const float4 f0 = sp[0], f1 = sp[1];
                v[0]=f0.x; v[1]=f0.y; v[2]=f0.z; v[3]=f0.w;
                v[4]=f1.x; v[5]=f1.y; v[6]=f1.z; v[7]=f1.w;
            } else {
#pragma unroll
                for (int i = 0; i < 8; ++i) v[i] = 0.f;
            }
            short8 p;
#pragma unroll
            for (int i = 0; i < 8; ++i) p[i] = (short)f2b(v[i]);
            *(short8*)(fs + bt*392 + cc) = p;
        }
        // ---- x_v-derived: 8 ch per half at 64-ch stride
        {
            const float r0 = rhp[(bt*3+k)*4+0];
            const float r1 = rhp[(bt*3+k)*4+1];
            const float r2 = rhp[(bt*3+k)*4+2];
#pragma unroll
            for (int hh = 0; hh < 2; ++hh) {
                const int cb = bx*8 + hh*64;
                float vv[24];
                if (valid) {
                    const float4* vp = (const float4*)(x_v + ((size_t)j*128 + cb)*3);
#pragma unroll
                    for (int i = 0; i < 6; ++i) {
                        const float4 f = vp[i];
                        vv[4*i]=f.x; vv[4*i+1]=f.y; vv[4*i+2]=f.z; vv[4*i+3]=f.w;
                    }
                } else {
#pragma unroll
                    for (int i = 0; i < 24; ++i) vv[i] = 0.f;
                }
                short8 dv, w0, w1, w2, x0, x1, x2;
#pragma unroll
                for (int m = 0; m < 8; ++m) {
                    const float a0 = vv[3*m], a1 = vv[3*m+1], a2 = vv[3*m+2];
                    dv[m] = (short)f2b(a0*r0 + a1*r1 + a2*r2);
                    w0[m] = (short)f2b(a0); w1[m] = (short)f2b(a1); w2[m] = (short)f2b(a2);
                    x0[m] = (short)f2b(a1*r2 - a2*r1);
                    x1[m] = (short)f2b(a2*r0 - a0*r2);
                    x2[m] = (short)f2b(a0*r1 - a1*r0);
                }
                *(short8*)(fs + bt*392 + 256 + cb)        = dv;
                *(short8*)(fv + (0*64+bt)*264 + cb)       = w0;
                *(short8*)(fv + (1*64+bt)*264 + cb)       = w1;
                *(short8*)(fv + (2*64+bt)*264 + cb)       = w2;
                *(short8*)(fv + (0*64+bt)*264 + 128 + cb) = x0;
                *(short8*)(fv + (1*64+bt)*264 + 128 + cb) = x1;
                *(short8*)(fv + (2*64+bt)*264 + 128 + cb) = x2;
            }
        }
        __syncthreads();

        const u16* rowS0 = wt + OFF_CS + k*384 + (size_t)((2*w+0)*16+lm)*1152;
        const u16* rowS1 = wt + OFF_CS + k*384 + (size_t)((2*w+1)*16+lm)*1152;
        const u16* rowG0 = wt + OFF_G + k*256 + (size_t)(ch*64 +  0+lm)*768;
        const u16* rowG1 = wt + OFF_G + k*256 + (size_t)(ch*64 + 16+lm)*768;
        const u16* rowG2 = wt + OFF_G + k*256 + (size_t)(ch*64 + 32+lm)*768;
        const u16* rowG3 = wt + OFF_G + k*256 + (size_t)(ch*64 + 48+lm)*768;
        const u16* rowV0 = wt + OFF_V + k*256 + (size_t)(ch*64 +  0+lm)*768;
        const u16* rowV1 = wt + OFF_V + k*256 + (size_t)(ch*64 + 16+lm)*768;
        const u16* rowV2 = wt + OFF_V + k*256 + (size_t)(ch*64 + 32+lm)*768;
        const u16* rowV3 = wt + OFF_V + k*256 + (size_t)(ch*64 + 48+lm)*768;

        // ---- scalar conv (K=384) + g (K=256)
        f32x4 agc[4] = {fz, fz, fz, fz};   // g for tokens tq*16, cols ch*64+j*16
#pragma unroll
        for (int ks = 0; ks < 12; ++ks) {
            const int ko = ks*32 + lk8;
            const short8 b0 = *(const short8*)(rowS0 + ko);
            const short8 b1 = *(const short8*)(rowS1 + ko);
#pragma unroll
            for (int m = 0; m < 4; ++m) {
                const short8 a = *(const short8*)(fs + (m*16+lm)*392 + ko);
                acc_s[m][0] = MFMA(a, b0, acc_s[m][0]);
                acc_s[m][1] = MFMA(a, b1, acc_s[m][1]);
            }
            if (ks < 8) {
                const short8 ag = *(const short8*)(fs + (tq*16+lm)*392 + ko);
                agc[0] = MFMA(ag, *(const short8*)(rowG0 + ko), agc[0]);
                agc[1] = MFMA(ag, *(const short8*)(rowG1 + ko), agc[1]);
                agc[2] = MFMA(ag, *(const short8*)(rowG2 + ko), agc[2]);
                agc[3] = MFMA(ag, *(const short8*)(rowG3 + ko), agc[3]);
            }
        }
        // ---- vec conv: 3 d-frags (tokens tq*16) x 4 col-frags
#pragma unroll
        for (int ks = 0; ks < 8; ++ks) {
            const int ko = ks*32 + lk8;
            const short8 bv0 = *(const short8*)(rowV0 + ko);
            const short8 bv1 = *(const short8*)(rowV1 + ko);
            const short8 bv2 = *(const short8*)(rowV2 + ko);
            const short8 bv3 = *(const short8*)(rowV3 + ko);
#pragma unroll
            for (int d = 0; d < 3; ++d) {
                const short8 a = *(const short8*)(fv + (d*64 + tq*16 + lm)*264 + ko);
                accv[d][0] = MFMA(a, bv0, accv[d][0]);
                accv[d][1] = MFMA(a, bv1, accv[d][1]);
                accv[d][2] = MFMA(a, bv2, accv[d][2]);
                accv[d][3] = MFMA(a, bv3, accv[d][3]);
            }
        }
        // ---- fold g into accv (token t = tq*16+lq4+q)
#pragma unroll
        for (int d = 0; d < 3; ++d)
#pragma unroll
            for (int j2 = 0; j2 < 4; ++j2)
#pragma unroll
                for (int q = 0; q < 4; ++q) {
                    const int t = tq*16 + lq4 + q;
                    accv[d][j2][q] += agc[j2][q] * rhp[(t*3+k)*4+d];
                }
        __syncthreads();
    }

    // ---- fan-in scales
    const float inv_fs = 0.029462783f;     // 1/sqrt(1152)
    const float inv_fv = 0.0255155136f;    // 1/sqrt(1536)
#pragma unroll
    for (int m = 0; m < 4; ++m)
#pragma unroll
        for (int u = 0; u < 2; ++u)
#pragma unroll
            for (int q = 0; q < 4; ++q) acc_s[m][u][q] *= inv_fs;
#pragma unroll
    for (int d = 0; d < 3; ++d)
#pragma unroll
        for (int j2 = 0; j2 < 4; ++j2)
#pragma unroll
            for (int q = 0; q < 4; ++q) accv[d][j2][q] *= inv_fv;

    // ---- LN1
    float p1[4][4], p2[4][4], pv[4][4], mu[4][4], ss[4][4], vs[4][4];
#pragma unroll
    for (int m = 0; m < 4; ++m)
#pragma unroll
        for (int q = 0; q < 4; ++q) {
            float a = 0.f, b = 0.f;
#pragma unroll
            for (int u = 0; u < 2; ++u) { const float x = acc_s[m][u][q]; a += x; b += x*x; }
            p1[m][q] = a; p2[m][q] = b;
            float c = 0.f;
            if (m == tq) {
#pragma unroll
                for (int d = 0; d < 3; ++d)
#pragma unroll
                    for (int j2 = 0; j2 < 4; ++j2) { const float x = accv[d][j2][q]; c += x*x; }
            }
            pv[m][q] = c;
        }
    ln_reduce(p1, p2, pv, red, lm, lq4, w, mu, ss, vs);
    float vst[4];
#pragma unroll
    for (int q = 0; q < 4; ++q)
        vst[q] = (tq==0) ? vs[0][q] : (tq==1) ? vs[1][q] : (tq==2) ? vs[2][q] : vs[3][q];

    // apply LN1 + bf16 staging for SI
#pragma unroll
    for (int m = 0; m < 4; ++m)
#pragma unroll
        for (int u = 0; u < 2; ++u)
#pragma unroll
            for (int q = 0; q < 4; ++q) {
                const float h = (acc_s[m][u][q] - mu[m][q]) * ss[m][q];
                acc_s[m][u][q] = h;
                hsb[(m*16+lq4+q)*264 + (2*w+u)*16 + lm] = f2b(h);
            }
#pragma unroll
    for (int d = 0; d < 3; ++d)
#pragma unroll
        for (int j2 = 0; j2 < 4; ++j2)
#pragma unroll
            for (int q = 0; q < 4; ++q) {
                const float h = accv[d][j2][q] * vst[q];
                accv[d][j2][q] = h;
                hvb[(d*64 + tq*16 + lq4 + q)*136 + ch*64 + j2*16 + lm] = f2b(h);
            }
    __syncthreads();

    // ---- SI GEMMs
    {
        const u16* rowP0 = wt + OFF_SS + (size_t)((2*w+0)*16+lm)*256;
        const u16* rowP1 = wt + OFF_SS + (size_t)((2*w+1)*16+lm)*256;
        f32x4 accs[4][2];
#pragma unroll
        for (int m = 0; m < 4; ++m) { accs[m][0] = fz; accs[m][1] = fz; }
#pragma unroll
        for (int ks = 0; ks < 8; ++ks) {
            const int ko = ks*32 + lk8;
            const short8 c0 = *(const short8*)(rowP0 + ko);
            const short8 c1 = *(const short8*)(rowP1 + ko);
#pragma unroll
            for (int m = 0; m < 4; ++m) {
                const short8 a = *(const short8*)(hsb + (m*16+lm)*264 + ko);
                accs[m][0] = MFMA(a, c0, accs[m][0]);
                accs[m][1] = MFMA(a, c1, accs[m][1]);
            }
        }
#pragma unroll
        for (int m = 0; m < 4; ++m)
#pragma unroll
            for (int u = 0; u < 2; ++u)
#pragma unroll
                for (int q = 0; q < 4; ++q) acc_s[m][u][q] += accs[m][u][q] * 0.0625f;
    }
    {
        const u16* rowQ0 = wt + OFF_SV + (size_t)(ch*64 +  0+lm)*128;
        const u16* rowQ1 = wt + OFF_SV + (size_t)(ch*64 + 16+lm)*128;
        const u16* rowQ2 = wt + OFF_SV + (size_t)(ch*64 + 32+lm)*128;
        const u16* rowQ3 = wt + OFF_SV + (size_t)(ch*64 + 48+lm)*128;
        f32x4 accw[3][4];
#pragma unroll
        for (int d = 0; d < 3; ++d)
#pragma unroll
            for (int j2 = 0; j2 < 4; ++j2) accw[d][j2] = fz;
#pragma unroll
        for (int ks = 0; ks < 4; ++ks) {
            const int ko = ks*32 + lk8;
            const short8 c0 = *(const short8*)(rowQ0 + ko);
            const short8 c1 = *(const short8*)(rowQ1 + ko);
            const short8 c2 = *(const short8*)(rowQ2 + ko);
            const short8 c3 = *(const short8*)(rowQ3 + ko);
#pragma unroll
            for (int d = 0; d < 3; ++d) {
                const short8 a = *(const short8*)(hvb + (d*64 + tq*16 + lm)*136 + ko);
                accw[d][0] = MFMA(a, c0, accw[d][0]);
                accw[d][1] = MFMA(a, c1, accw[d][1]);
                accw[d][2] = MFMA(a, c2, accw[d][2]);
                accw[d][3] = MFMA(a, c3, accw[d][3]);
            }
        }
#pragma unroll
        for (int d = 0; d < 3; ++d)
#pragma unroll
            for (int j2 = 0; j2 < 4; ++j2)
#pragma unroll
                for (int q = 0; q < 4; ++q)
                    accv[d][j2][q] += accw[d][j2][q] * 0.08838834764f;
    }

    // ---- LN2 partials + early x_v residual loads
#pragma unroll
    for (int m = 0; m < 4; ++m)
#pragma unroll
        for (int q = 0; q < 4; ++q) {
            float a = 0.f, b = 0.f;
#pragma unroll
            for (int u = 0; u < 2; ++u) { const float x = acc_s[m][u][q]; a += x; b += x*x; }
            p1[m][q] = a; p2[m][q] = b;
            float c = 0.f;
            if (m == tq) {
#pragma unroll
                for (int d = 0; d < 3; ++d)
#pragma unroll
                    for (int j2 = 0; j2 < 4; ++j2) { const float x = accv[d][j2][q]; c += x*x; }
            }
            pv[m][q] = c;
        }
    float4 xr[12];
    {
        const float4* xvsrc = (const float4*)(x_v + (size_t)gt0 * 384);
#pragma unroll
        for (int i = 0; i < 12; ++i) xr[i] = xvsrc[tid + i*512];
    }
    ln_reduce(p1, p2, pv, red, lm, lq4, w, mu, ss, vs);  // entry barrier fences hvb reads
#pragma unroll
    for (int q = 0; q < 4; ++q)
        vst[q] = (tq==0) ? vs[0][q] : (tq==1) ? vs[1][q] : (tq==2) ? vs[2][q] : vs[3][q];
#pragma unroll
    for (int i = 0; i < 12; ++i) ((float4*)xvL)[tid + i*512] = xr[i];
    __syncthreads();

    // ---- apply LN2 + residuals
#pragma unroll
    for (int m = 0; m < 4; ++m)
#pragma unroll
        for (int u = 0; u < 2; ++u)
#pragma unroll
            for (int q = 0; q < 4; ++q)
                acc_s[m][u][q] = (acc_s[m][u][q] - mu[m][q]) * ss[m][q]
                    + x_s[(size_t)(gt0 + m*16 + lq4 + q)*256 + (2*w+u)*16 + lm];
#pragma unroll
    for (int d = 0; d < 3; ++d)
#pragma unroll
        for (int j2 = 0; j2 < 4; ++j2)
#pragma unroll
            for (int q = 0; q < 4; ++q) {
                const int t = tq*16 + lq4 + q;
                accv[d][j2][q] = accv[d][j2][q] * vst[q]
                    + xvL[t*384 + (ch*64 + j2*16 + lm)*3 + d];
            }

    // ---- LN3
#pragma unroll
    for (int m = 0; m < 4; ++m)
#pragma unroll
        for (int q = 0; q < 4; ++q) {
            float a = 0.f, b = 0.f;
#pragma unroll
            for (int u = 0; u < 2; ++u) { const float x = acc_s[m][u][q]; a += x; b += x*x; }
            p1[m][q] = a; p2[m][q] = b;
            float c = 0.f;
            if (m == tq) {
#pragma unroll
                for (int d = 0; d < 3; ++d)
#pragma unroll
                    for (int j2 = 0; j2 < 4; ++j2) { const float x = accv[d][j2][q]; c += x*x; }
            }
            pv[m][q] = c;
        }
    ln_reduce(p1, p2, pv, red, lm, lq4, w, mu, ss, vs);
#pragma unroll
    for (int q = 0; q < 4; ++q)
        vst[q] = (tq==0) ? vs[0][q] : (tq==1) ? vs[1][q] : (tq==2) ? vs[2][q] : vs[3][q];

    // z_s: direct store
#pragma unroll
    for (int m = 0; m < 4; ++m)
#pragma unroll
        for (int u = 0; u < 2; ++u)
#pragma unroll
            for (int q = 0; q < 4; ++q)
                out[(size_t)(gt0 + m*16 + lq4 + q)*256 + (2*w+u)*16 + lm] =
                    (acc_s[m][u][q] - mu[m][q]) * ss[m][q];
    // z_v: stage in LDS, then coalesced NT float4 copy
#pragma unroll
    for (int d = 0; d < 3; ++d)
#pragma unroll
        for (int j2 = 0; j2 < 4; ++j2)
#pragma unroll
            for (int q = 0; q < 4; ++q) {
                const int t = tq*16 + lq4 + q;
                xvL[t*384 + (ch*64 + j2*16 + lm)*3 + d] = accv[d][j2][q] * vst[q];
            }
    __syncthreads();
    {
        f32x4* dst = (f32x4*)(out + ZV0 + (size_t)gt0 * 384);
        const f32x4* srcv = (const f32x4*)xvL;
#pragma unroll
        for (int i = 0; i < 12; ++i)
            __builtin_nontemporal_store(srcv[tid + i*512], dst + tid + i*512);
    }
}

extern "C" void kernel_launch(void* const* d_in, const int* in_sizes, int n_in,
                              void* d_out, int out_size, void* d_ws, size_t ws_size,
                              hipStream_t stream) {
    const float* x_s    = (const float*)d_in[0];
    const float* x_v    = (const float*)d_in[1];
    const float* coords = (const float*)d_in[2];
    const float* Wcs    = (const float*)d_in[3];
    const float* Wcv    = (const float*)d_in[4];
    const float* Wss    = (const float*)d_in[5];
    const float* Wsv    = (const float*)d_in[6];
    float* out = (float*)d_out;
    u16* ws = (u16*)d_ws;

    hipLaunchKernelGGL(prep_weights, dim3(560), dim3(256), 0, stream,
                       Wcs, Wcv, Wss, Wsv, ws);
    hipLaunchKernelGGL(mixing_main, dim3((B_ * N_) / TB), dim3(512), 0, stream,
                       x_s, x_v, coords, ws, out);
}

// Round 12
// 101.189 us; speedup vs baseline: 2.9848x; 2.9848x over previous
//
#include <hip/hip_runtime.h>
#include <hip/hip_bf16.h>

// MixingBlock round 12: R9 base (TB=64, 512thr, 1 block/CU, rings kept).
// Changes: (1) two-stage LN finalize — red[] cross-wave sum done once by
// wave 0, lanes read 16 (not 128) b128 per reduce; (2) xvL stride 384->388
// f32 to kill 4-way bank conflicts on scalar z_v/residual LDS accesses.

typedef __attribute__((ext_vector_type(8))) short short8;
typedef __attribute__((ext_vector_type(4))) short short4v;
typedef __attribute__((ext_vector_type(4))) float f32x4;
typedef unsigned short u16;

#define B_   8
#define N_   2048
#define EPS_ 1e-6f
#define TB   64

// ws element offsets (bf16)
#define OFF_CS 0        // wt_cs [256][1152]  (k*384 col blocks: [s_win|vdot])
#define OFF_V  294912   // wt_v  [128][768]   (k*256: [vwin(128)|cross(128)])
#define OFF_G  393216   // wt_g  [128][768]   (k*256: s_rhat weights)
#define OFF_SS 491520   // wt_ss [256][256]
#define OFF_SV 557056   // wt_sv [128][128]

#define MFMA(a,b,c) __builtin_amdgcn_mfma_f32_16x16x32_bf16((a),(b),(c),0,0,0)

__device__ __forceinline__ u16 f2b(float v){ __hip_bfloat16 h=__float2bfloat16(v); return *(u16*)&h; }

// ---------------- weight prep: transpose + remap + f32->bf16 ----------------
__global__ __launch_bounds__(256) void prep_weights(
    const float* __restrict__ Wcs, const float* __restrict__ Wcv,
    const float* __restrict__ Wss, const float* __restrict__ Wsv,
    u16* __restrict__ ws)
{
    const int bid = blockIdx.x;
    const float* src; int N, r0, ld, c0; u16* dst; int tile;
    if (bid < 288)      { src=Wcs; N=256; r0=0; dst=ws+OFF_CS; ld=1152; c0=0; tile=bid; }
    else if (bid < 336) { int k=(bid-288)/16; tile=(bid-288)%16;
                          src=Wcv; N=128; r0=k*512;     dst=ws+OFF_V; ld=768; c0=k*256; }
    else if (bid < 432) { int k=(bid-336)/32; tile=(bid-336)%32;
                          src=Wcv; N=128; r0=k*512+128; dst=ws+OFF_G; ld=768; c0=k*256; }
    else if (bid < 480) { int k=(bid-432)/16; tile=(bid-432)%16;
                          src=Wcv; N=128; r0=k*512+384; dst=ws+OFF_V; ld=768; c0=k*256+128; }
    else if (bid < 544) { tile=bid-480; src=Wss; N=256; r0=0; dst=ws+OFF_SS; ld=256; c0=0; }
    else                { tile=bid-544; src=Wsv; N=128; r0=0; dst=ws+OFF_SV; ld=128; c0=0; }
    const int ntN = N >> 5;
    const int kt = (tile/ntN)*32, nn = (tile%ntN)*32;
    __shared__ float t[32][33];
    const int r = threadIdx.x >> 5, c = threadIdx.x & 31;
#pragma unroll
    for (int i = 0; i < 4; ++i)
        t[r+8*i][c] = src[(size_t)(r0+kt+r+8*i)*N + nn+c];
    __syncthreads();
#pragma unroll
    for (int i = 0; i < 4; ++i)
        dst[(size_t)(nn+r+8*i)*ld + c0+kt+c] = f2b(t[c][r+8*i]);
}

// LN reduce, two-stage: 16-lane butterfly -> red[t][w] partials -> wave 0
// finalizes per-token {mu,ss,vs} into swizzled slot -> all lanes read 16 b128.
__device__ __forceinline__ void ln_reduce(
    float p1[4][4], float p2[4][4], float pv[4][4], f32x4* red,
    int tid, int lm, int lq4, int w,
    float mu[4][4], float ss[4][4], float vs[4][4])
{
    __syncthreads();
#pragma unroll
    for (int m2 = 1; m2 < 16; m2 <<= 1)
#pragma unroll
        for (int m = 0; m < 4; ++m)
#pragma unroll
            for (int q = 0; q < 4; ++q) {
                p1[m][q] += __shfl_xor(p1[m][q], m2);
                p2[m][q] += __shfl_xor(p2[m][q], m2);
                pv[m][q] += __shfl_xor(pv[m][q], m2);
            }
    if (lm == 0)
#pragma unroll
        for (int m = 0; m < 4; ++m)
#pragma unroll
            for (int q = 0; q < 4; ++q) {
                f32x4 r = {p1[m][q], p2[m][q], pv[m][q], 0.f};
                red[(m*16+lq4+q)*8 + w] = r;
            }
    __syncthreads();
    if (tid < 64) {
        const int t = tid;
        f32x4 rs = red[t*8+0];
#pragma unroll
        for (int i = 1; i < 8; ++i) rs += red[t*8+i];
        const float mm = rs.x * (1.f/256.f);
        f32x4 fin;
        fin.x = mm;
        fin.y = rsqrtf(rs.y*(1.f/256.f) - mm*mm + EPS_);
        fin.z = rsqrtf(rs.z*(1.f/128.f) + EPS_);
        fin.w = 0.f;
        red[t*8 + (t&7)] = fin;        // swizzled slot: bank spread
    }
    __syncthreads();
#pragma unroll
    for (int m = 0; m < 4; ++m)
#pragma unroll
        for (int q = 0; q < 4; ++q) {
            const int t = m*16 + lq4 + q;
            const f32x4 fin = red[t*8 + (t&7)];
            mu[m][q] = fin.x; ss[m][q] = fin.y; vs[m][q] = fin.z;
        }
}

__global__ __launch_bounds__(512, 2) void mixing_main(
    const float* __restrict__ x_s, const float* __restrict__ x_v,
    const float* __restrict__ coords, const u16* __restrict__ wt,
    float* __restrict__ out)
{
    // fs [64][392]u16 @0 | fv [192][264]u16 @50176 | rhp @151552 | red @154624
    // aliases: hsb [64][264]@0, hvb [192][136]@50176, xvL [64][388]f32 @50176
    __shared__ __align__(16) char smem[162816];
    u16*   fs  = (u16*)smem;
    u16*   fv  = (u16*)(smem + 50176);
    u16*   hsb = (u16*)smem;
    u16*   hvb = (u16*)(smem + 50176);
    float* xvL = (float*)(smem + 50176);   // padded stride 388 f32/token
    float* rhp = (float*)(smem + 151552);
    f32x4* red = (f32x4*)(smem + 154624);

    const int tid = threadIdx.x;
    const int w   = tid >> 6, l = tid & 63;
    const int lm  = l & 15, lk8 = (l >> 4) << 3, lq4 = (l >> 4) << 2;
    const int gt0 = blockIdx.x * TB;
    const int n0  = gt0 & (N_ - 1);
    const int seq0 = gt0 - n0;
    const size_t ZV0 = (size_t)B_ * N_ * 256;

    // rhat [64 t][3 k]
    if (tid < 192) {
        const int t = tid / 3, k = tid - 3 * (tid / 3);
        const int jn = n0 + t + k - 1;
        const int jc = jn < 0 ? 0 : (jn > N_-1 ? N_-1 : jn);
        const float* cj = coords + (size_t)(seq0 + jc) * 3;
        const float* c0p = coords + (size_t)(gt0 + t) * 3;
        const float d0 = cj[0]-c0p[0], d1 = cj[1]-c0p[1], d2 = cj[2]-c0p[2];
        const float dn = sqrtf(d0*d0 + d1*d1 + d2*d2);
        const float inv = dn > 1e-6f ? 1.f/dn : 0.f;
        rhp[(t*3+k)*4+0] = d0*inv; rhp[(t*3+k)*4+1] = d1*inv; rhp[(t*3+k)*4+2] = d2*inv;
    }
    __syncthreads();

    const f32x4 fz = {0.f,0.f,0.f,0.f};
    f32x4 acc_s[4][2];                     // [m][u]
    f32x4 accv[12];                        // mi = d*4 + m
#pragma unroll
    for (int m = 0; m < 4; ++m) { acc_s[m][0] = fz; acc_s[m][1] = fz; }
#pragma unroll
    for (int mi = 0; mi < 12; ++mi) accv[mi] = fz;

    const int bt = tid >> 3;   // token 0..63
    const int bx = tid & 7;

#pragma unroll 1
    for (int k = 0; k < 3; ++k) {
        const int jn = n0 + bt + k - 1;
        const bool valid = (unsigned)jn < (unsigned)N_;
        const size_t j = (size_t)seq0 + (valid ? jn : 0);
        // ---- s_win: 32 channels/thread
        {
            const int c0 = bx * 32;
            const float4* sp = (const float4*)(x_s + j*256 + c0);
#pragma unroll
            for (int h = 0; h < 4; ++h) {
                float v[8];
                if (valid) {
                    const float4 f0 = sp[2*h], f1 = sp[2*h+1];
                    v[0]=f0.x; v[1]=f0.y; v[2]=f0.z; v[3]=f0.w;
                    v[4]=f1.x; v[5]=f1.y; v[6]=f1.z; v[7]=f1.w;
                } else {
#pragma unroll
                    for (int i = 0; i < 8; ++i) v[i] = 0.f;
                }
                short8 p;
#pragma unroll
                for (int i = 0; i < 8; ++i) p[i] = (short)f2b(v[i]);
                *(short8*)(fs + bt*392 + c0 + 8*h) = p;
            }
        }
        // ---- x_v-derived: vdot / vwin / cross, 16 ch/thread in 2 halves
        {
            const int ch0 = bx * 16;
            const float r0 = rhp[(bt*3+k)*4+0];
            const float r1 = rhp[(bt*3+k)*4+1];
            const float r2 = rhp[(bt*3+k)*4+2];
#pragma unroll
            for (int hh = 0; hh < 2; ++hh) {
                const int cb = ch0 + 8*hh;
                float vv[24];
                if (valid) {
                    const float4* vp = (const float4*)(x_v + ((size_t)j*128 + cb)*3);
#pragma unroll
                    for (int i = 0; i < 6; ++i) {
                        const float4 f = vp[i];
                        vv[4*i]=f.x; vv[4*i+1]=f.y; vv[4*i+2]=f.z; vv[4*i+3]=f.w;
                    }
                } else {
#pragma unroll
                    for (int i = 0; i < 24; ++i) vv[i] = 0.f;
                }
                short8 dv, w0, w1, w2, x0, x1, x2;
#pragma unroll
                for (int m = 0; m < 8; ++m) {
                    const float a0 = vv[3*m], a1 = vv[3*m+1], a2 = vv[3*m+2];
                    dv[m] = (short)f2b(a0*r0 + a1*r1 + a2*r2);
                    w0[m] = (short)f2b(a0); w1[m] = (short)f2b(a1); w2[m] = (short)f2b(a2);
                    x0[m] = (short)f2b(a1*r2 - a2*r1);
                    x1[m] = (short)f2b(a2*r0 - a0*r2);
                    x2[m] = (short)f2b(a0*r1 - a1*r0);
                }
                *(short8*)(fs + bt*392 + 256 + cb)            = dv;
                *(short8*)(fv + (0*64+bt)*264 + cb)           = w0;
                *(short8*)(fv + (1*64+bt)*264 + cb)           = w1;
                *(short8*)(fv + (2*64+bt)*264 + cb)           = w2;
                *(short8*)(fv + (0*64+bt)*264 + 128 + cb)     = x0;
                *(short8*)(fv + (1*64+bt)*264 + 128 + cb)     = x1;
                *(short8*)(fv + (2*64+bt)*264 + 128 + cb)     = x2;
            }
        }

        // ---- ring fill before barrier (latency drains with it)
        const u16* bS0 = wt + OFF_CS + k*384 + (size_t)((2*w+0)*16+lm)*1152;
        const u16* bS1 = wt + OFF_CS + k*384 + (size_t)((2*w+1)*16+lm)*1152;
        const u16* bGp = wt + OFF_G  + k*256 + (size_t)(w*16+lm)*768;
        const u16* bVp = wt + OFF_V  + k*256 + (size_t)(w*16+lm)*768;
        short8 Bs0[3], Bs1[3], Bg[3], Bv[4];
#pragma unroll
        for (int i = 0; i < 3; ++i) {
            Bs0[i] = *(const short8*)(bS0 + i*32 + lk8);
            Bs1[i] = *(const short8*)(bS1 + i*32 + lk8);
            Bg[i]  = *(const short8*)(bGp + i*32 + lk8);
        }
        __syncthreads();

        // ---- scalar conv (K=384) + g (K=256): 4 m-frags share each b
        f32x4 agc[4] = {fz, fz, fz, fz};
#pragma unroll
        for (int ks = 0; ks < 12; ++ks) {
            const int r = ks % 3;
            const short8 b0 = Bs0[r], b1 = Bs1[r], bg = Bg[r];
            if (ks + 3 < 12) {
                Bs0[r] = *(const short8*)(bS0 + (ks+3)*32 + lk8);
                Bs1[r] = *(const short8*)(bS1 + (ks+3)*32 + lk8);
            }
            if (ks + 3 < 8)
                Bg[r] = *(const short8*)(bGp + (ks+3)*32 + lk8);
            if (ks == 9) {
#pragma unroll
                for (int i = 0; i < 4; ++i)
                    Bv[i] = *(const short8*)(bVp + i*32 + lk8);
            }
            const int ko = ks*32 + lk8;
#pragma unroll
            for (int m = 0; m < 4; ++m) {
                const short8 a = *(const short8*)(fs + (m*16+lm)*392 + ko);
                acc_s[m][0] = MFMA(a, b0, acc_s[m][0]);
                acc_s[m][1] = MFMA(a, b1, acc_s[m][1]);
                if (ks < 8) agc[m] = MFMA(a, bg, agc[m]);
            }
        }
        // ---- vec conv: [192 x 256] x [256 x 128], 12 m-frags share each b
#pragma unroll
        for (int ks = 0; ks < 8; ++ks) {
            const int r = ks & 3;
            const short8 bv = Bv[r];
            if (ks + 4 < 8)
                Bv[r] = *(const short8*)(bVp + (ks+4)*32 + lk8);
            const int ko = ks*32 + lk8;
#pragma unroll
            for (int mi = 0; mi < 12; ++mi) {
                const short8 a = *(const short8*)(
                    fv + ((mi>>2)*64 + (mi&3)*16 + lm)*264 + ko);
                accv[mi] = MFMA(a, bv, accv[mi]);
            }
        }
        // ---- fold g
#pragma unroll
        for (int mi = 0; mi < 12; ++mi) {
            const int m = mi & 3, d = mi >> 2;
#pragma unroll
            for (int q = 0; q < 4; ++q)
                accv[mi][q] += agc[m][q] * rhp[((m*16+lq4+q)*3 + k)*4 + d];
        }
        __syncthreads();
    }

    // ---- fan-in scales
    const float inv_fs = 0.029462783f;     // 1/sqrt(1152)
    const float inv_fv = 0.0255155136f;    // 1/sqrt(1536)
#pragma unroll
    for (int m = 0; m < 4; ++m)
#pragma unroll
        for (int u = 0; u < 2; ++u)
#pragma unroll
            for (int q = 0; q < 4; ++q) acc_s[m][u][q] *= inv_fs;
#pragma unroll
    for (int mi = 0; mi < 12; ++mi)
#pragma unroll
        for (int q = 0; q < 4; ++q) accv[mi][q] *= inv_fv;

    // ---- LN1
    float p1[4][4], p2[4][4], pv[4][4], mu[4][4], ss[4][4], vs[4][4];
#pragma unroll
    for (int m = 0; m < 4; ++m)
#pragma unroll
        for (int q = 0; q < 4; ++q) {
            float a = 0.f, b = 0.f, c = 0.f;
#pragma unroll
            for (int u = 0; u < 2; ++u) { const float x = acc_s[m][u][q]; a += x; b += x*x; }
#pragma unroll
            for (int d = 0; d < 3; ++d) { const float x = accv[d*4+m][q]; c += x*x; }
            p1[m][q] = a; p2[m][q] = b; pv[m][q] = c;
        }
    ln_reduce(p1, p2, pv, red, tid, lm, lq4, w, mu, ss, vs);

    // apply LN1 + bf16 staging for SI
#pragma unroll
    for (int m = 0; m < 4; ++m)
#pragma unroll
        for (int u = 0; u < 2; ++u)
#pragma unroll
            for (int q = 0; q < 4; ++q) {
                const float h = (acc_s[m][u][q] - mu[m][q]) * ss[m][q];
                acc_s[m][u][q] = h;
                hsb[(m*16+lq4+q)*264 + (2*w+u)*16 + lm] = f2b(h);
            }
#pragma unroll
    for (int mi = 0; mi < 12; ++mi)
#pragma unroll
        for (int q = 0; q < 4; ++q) {
            const float h = accv[mi][q] * vs[mi&3][q];
            accv[mi][q] = h;
            hvb[((mi>>2)*64 + (mi&3)*16 + lq4 + q)*136 + w*16 + lm] = f2b(h);
        }

    // ---- SI rings before barrier
    const u16* bP0 = wt + OFF_SS + (size_t)((2*w+0)*16+lm)*256;
    const u16* bP1 = wt + OFF_SS + (size_t)((2*w+1)*16+lm)*256;
    const u16* bPv = wt + OFF_SV + (size_t)(w*16+lm)*128;
    short8 Cs0[3], Cs1[3], Cv[4];
#pragma unroll
    for (int i = 0; i < 3; ++i) {
        Cs0[i] = *(const short8*)(bP0 + i*32 + lk8);
        Cs1[i] = *(const short8*)(bP1 + i*32 + lk8);
    }
#pragma unroll
    for (int i = 0; i < 4; ++i)
        Cv[i] = *(const short8*)(bPv + i*32 + lk8);
    __syncthreads();

    // ---- SI GEMMs
    f32x4 accs[4][2];
    f32x4 accw[12];
#pragma unroll
    for (int m = 0; m < 4; ++m) { accs[m][0] = fz; accs[m][1] = fz; }
#pragma unroll
    for (int mi = 0; mi < 12; ++mi) accw[mi] = fz;
#pragma unroll
    for (int ks = 0; ks < 8; ++ks) {
        const int r = ks % 3;
        const short8 c0 = Cs0[r], c1 = Cs1[r];
        if (ks + 3 < 8) {
            Cs0[r] = *(const short8*)(bP0 + (ks+3)*32 + lk8);
            Cs1[r] = *(const short8*)(bP1 + (ks+3)*32 + lk8);
        }
        const int ko = ks*32 + lk8;
#pragma unroll
        for (int m = 0; m < 4; ++m) {
            const short8 a = *(const short8*)(hsb + (m*16+lm)*264 + ko);
            accs[m][0] = MFMA(a, c0, accs[m][0]);
            accs[m][1] = MFMA(a, c1, accs[m][1]);
        }
    }
#pragma unroll
    for (int ks = 0; ks < 4; ++ks) {
        const int ko = ks*32 + lk8;
#pragma unroll
        for (int mi = 0; mi < 12; ++mi) {
            const short8 a = *(const short8*)(
                hvb + ((mi>>2)*64 + (mi&3)*16 + lm)*136 + ko);
            accw[mi] = MFMA(a, Cv[ks], accw[mi]);
        }
    }

    // ---- y = h + SI
#pragma unroll
    for (int m = 0; m < 4; ++m)
#pragma unroll
        for (int u = 0; u < 2; ++u)
#pragma unroll
            for (int q = 0; q < 4; ++q) acc_s[m][u][q] += accs[m][u][q] * 0.0625f;
#pragma unroll
    for (int mi = 0; mi < 12; ++mi)
#pragma unroll
        for (int q = 0; q < 4; ++q) accv[mi][q] += accw[mi][q] * 0.08838834764f;

    // ---- LN2 partials; x_v residual loads issued early
#pragma unroll
    for (int m = 0; m < 4; ++m)
#pragma unroll
        for (int q = 0; q < 4; ++q) {
            float a = 0.f, b = 0.f, c = 0.f;
#pragma unroll
            for (int u = 0; u < 2; ++u) { const float x = acc_s[m][u][q]; a += x; b += x*x; }
#pragma unroll
            for (int d = 0; d < 3; ++d) { const float x = accv[d*4+m][q]; c += x*x; }
            p1[m][q] = a; p2[m][q] = b; pv[m][q] = c;
        }
    float4 xr[12];
    {
        const float4* xvsrc = (const float4*)(x_v + (size_t)gt0 * 384);
#pragma unroll
        for (int i = 0; i < 12; ++i) xr[i] = xvsrc[tid + i*512];
    }
    ln_reduce(p1, p2, pv, red, tid, lm, lq4, w, mu, ss, vs);  // entry barrier fences hvb reads
#pragma unroll
    for (int i = 0; i < 12; ++i) {
        const int e4 = tid + i*512;
        const int t = e4 / 96, c4 = e4 - t*96;     // 96 float4 per token
        *(float4*)(xvL + t*388 + c4*4) = xr[i];
    }
    __syncthreads();

    // ---- apply LN2 + residuals
#pragma unroll
    for (int m = 0; m < 4; ++m)
#pragma unroll
        for (int u = 0; u < 2; ++u)
#pragma unroll
            for (int q = 0; q < 4; ++q)
                acc_s[m][u][q] = (acc_s[m][u][q] - mu[m][q]) * ss[m][q]
                    + x_s[(size_t)(gt0 + m*16 + lq4 + q)*256 + (2*w+u)*16 + lm];
#pragma unroll
    for (int mi = 0; mi < 12; ++mi)
#pragma unroll
        for (int q = 0; q < 4; ++q) {
            const int t = (mi&3)*16 + lq4 + q;
            accv[mi][q] = accv[mi][q] * vs[mi&3][q]
                + xvL[t*388 + (w*16+lm)*3 + (mi>>2)];
        }

    // ---- LN3
#pragma unroll
    for (int m = 0; m < 4; ++m)
#pragma unroll
        for (int q = 0; q < 4; ++q) {
            float a = 0.f, b = 0.f, c = 0.f;
#pragma unroll
            for (int u = 0; u < 2; ++u) { const float x = acc_s[m][u][q]; a += x; b += x*x; }
#pragma unroll
            for (int d = 0; d < 3; ++d) { const float x = accv[d*4+m][q]; c += x*x; }
            p1[m][q] = a; p2[m][q] = b; pv[m][q] = c;
        }
    ln_reduce(p1, p2, pv, red, tid, lm, lq4, w, mu, ss, vs);

    // z_s: direct store
#pragma unroll
    for (int m = 0; m < 4; ++m)
#pragma unroll
        for (int u = 0; u < 2; ++u)
#pragma unroll
            for (int q = 0; q < 4; ++q)
                out[(size_t)(gt0 + m*16 + lq4 + q)*256 + (2*w+u)*16 + lm] =
                    (acc_s[m][u][q] - mu[m][q]) * ss[m][q];
    // z_v: stage in padded LDS, then coalesced NT float4 copy
#pragma unroll
    for (int mi = 0; mi < 12; ++mi)
#pragma unroll
        for (int q = 0; q < 4; ++q) {
            const int t = (mi&3)*16 + lq4 + q;
            xvL[t*388 + (w*16+lm)*3 + (mi>>2)] = accv[mi][q] * vs[mi&3][q];
        }
    __syncthreads();
    {
        f32x4* dst = (f32x4*)(out + ZV0 + (size_t)gt0 * 384);
#pragma unroll
        for (int i = 0; i < 12; ++i) {
            const int e4 = tid + i*512;
            const int t = e4 / 96, c4 = e4 - t*96;
            const f32x4 v = *(const f32x4*)(xvL + t*388 + c4*4);
            __builtin_nontemporal_store(v, dst + e4);
        }
    }
}

extern "C" void kernel_launch(void* const* d_in, const int* in_sizes, int n_in,
                              void* d_out, int out_size, void* d_ws, size_t ws_size,
                              hipStream_t stream) {
    const float* x_s    = (const float*)d_in[0];
    const float* x_v    = (const float*)d_in[1];
    const float* coords = (const float*)d_in[2];
    const float* Wcs    = (const float*)d_in[3];
    const float* Wcv    = (const float*)d_in[4];
    const float* Wss    = (const float*)d_in[5];
    const float* Wsv    = (const float*)d_in[6];
    float* out = (float*)d_out;
    u16* ws = (u16*)d_ws;

    hipLaunchKernelGGL(prep_weights, dim3(560), dim3(256), 0, stream,
                       Wcs, Wcv, Wss, Wsv, ws);
    hipLaunchKernelGGL(mixing_main, dim3((B_ * N_) / TB), dim3(512), 0, stream,
                       x_s, x_v, coords, ws, out);
}